// Round 10
// baseline (164.752 us; speedup 1.0000x reference)
//
#include <hip/hip_runtime.h>
#include <math.h>

#define L_ 2
#define BAT_ 32
#define A_ 64
#define B_ 1024
#define D_ 128
#define NBITS_ 1024
#define NW 32                 // u32 words per code (1024 bits)
#define NQROWS (L_*BAT_*A_)   // 4096
#define NDROWS (L_*BAT_*B_)   // 65536
#define NROWS (NQROWS + NDROWS) // 69632
#define NAGRP (NROWS / 16)    // 4352 A-row groups of 16
#define NBGRP (NBITS_ / 16)   // 64 bit groups of 16

#define TM 128                // rows per tile
#define TN 128                // bits per tile
#define NXB (NROWS / TM)      // 544 x-tiles
#define NYB (NBITS_ / TN)     // 8 y-tiles
#define XPX (NXB / 8)         // 68 x-tiles per XCD
#define NTPB 4                // x-tiles per block (68 % 4 == 0)

typedef __bf16 bf16x8 __attribute__((ext_vector_type(8)));
typedef float  f32x4  __attribute__((ext_vector_type(4)));

// ---- Stage 0: split fp32 -> bf16 hi/lo AND swizzle into MFMA fragment order.
// UNCHANGED from R5 (verified).
__global__ __launch_bounds__(256) void preswz_kernel(
    const float* __restrict__ qe, const float* __restrict__ de,
    const float* __restrict__ r, __bf16* __restrict__ asw,
    __bf16* __restrict__ rsw)
{
    const int g = blockIdx.x;       // 0..4415: A groups then r groups
    const int t = threadIdx.x;
    const int ks = t >> 7, kk = (t >> 6) & 1, quad = (t >> 4) & 3, col = t & 15;

    const float* src;
    __bf16* dst;
    if (g < NAGRP) {
        int row = g * 16 + col;
        src = (row < NQROWS) ? (qe + (size_t)row * D_)
                             : (de + (size_t)(row - NQROWS) * D_);
        dst = asw + (size_t)g * 4096;
    } else {
        int bit = (g - NAGRP) * 16 + col;
        src = r + (size_t)bit * D_;
        dst = rsw + (size_t)(g - NAGRP) * 4096;
    }

    const int ko = ks * 64 + kk * 32 + quad * 8;
    float4 v0 = *(const float4*)(src + ko);
    float4 v1 = *(const float4*)(src + ko + 4);
    bf16x8 hi, lo;
    hi[0] = (__bf16)v0.x; hi[1] = (__bf16)v0.y;
    hi[2] = (__bf16)v0.z; hi[3] = (__bf16)v0.w;
    hi[4] = (__bf16)v1.x; hi[5] = (__bf16)v1.y;
    hi[6] = (__bf16)v1.z; hi[7] = (__bf16)v1.w;
    lo[0] = (__bf16)(v0.x - (float)hi[0]);
    lo[1] = (__bf16)(v0.y - (float)hi[1]);
    lo[2] = (__bf16)(v0.z - (float)hi[2]);
    lo[3] = (__bf16)(v0.w - (float)hi[3]);
    lo[4] = (__bf16)(v1.x - (float)hi[4]);
    lo[5] = (__bf16)(v1.y - (float)hi[5]);
    lo[6] = (__bf16)(v1.z - (float)hi[6]);
    lo[7] = (__bf16)(v1.w - (float)hi[7]);

    const int c_hi = ks * 16 + kk * 4 + quad;   // hl=0
    const int c_lo = c_hi + 8;                  // hl=1
    *(bf16x8*)(dst + (size_t)(c_hi * 16 + col) * 8) = hi;
    *(bf16x8*)(dst + (size_t)(c_lo * 16 + col) * 8) = lo;
}

// ---- Stage 1: LSH sign-hash — FAT WAVES: 4 waves x (64 rows x 64 bits) ----
// R10: per-CU round accounting for R5's structure: MFMA 1862 cyc, B-LDS 1024,
// A-L2 1170 — serial sum 4056 -> 46% util bound, matching the measured 38-46%
// across 7 probes (convoy: waves share phase, resources take turns).
// One change: 4 waves of 64x64 (was 8 of 32x64) per 128x128 tile:
//  * per ITER: 48 MFMA off 8 B-LDS + 8 A frags -> LDS cyc/round halves (512),
//    load-issue per MFMA halves, serial bound rises to ~53%, and each wave
//    has 16-deep independent MFMA batches for the scheduler.
//  * acc 64 + A x/y 64 + B 32 + addr -> ~185 regs, 256-quantum, 2 waves/SIMD
//    (R0 proved this wave shape at 140+ regs, no spill; B is now LDS-fed).
//  * XCD map / LDS staging / depth-1 A rotation / ballot epilogue: R5 exact.
__global__ __launch_bounds__(256, 2) void hash_kernel(
    const __bf16* __restrict__ asw, const __bf16* __restrict__ rsw,
    unsigned int* __restrict__ codes_t)
{
    __shared__ __align__(16) unsigned char bsh[65536];

    const int t = threadIdx.x;
    const int lane = t & 63;
    const int quad = lane >> 4;       // 0..3
    const int col  = lane & 15;       // 0..15
    const int wv   = __builtin_amdgcn_readfirstlane(t >> 6);  // wave 0..3

    const int bid = blockIdx.x;       // 0..1087
    const int xcd = bid & 7;
    const int s   = bid >> 3;         // 0..135
    const int by  = s & 7;
    const int xq  = s >> 3;           // 0..16
    const int bx0 = xcd * XPX + xq * NTPB;

    const int wrow = (wv >> 1) * 64;  // 2 wave-rows of 64
    const int half = wv & 1;          // 2 wave-cols of 64 bits

    // A frag (ti, cbi) at pointer P: P + (ti*8 + cbi)*512 elems, ti=0..3
    const __bf16* abase = asw + ((size_t)((bx0 * TM + wrow) >> 4)) * 4096
                              + (size_t)lane * 8;
#define ALOAD(P, ti, cbi) (*(const bf16x8*)((P) + ((ti) * 8 + (cbi)) * 512))
#define TILE_STRIDE 32768   /* 8 groups * 4096 elems */

    // B frag (tj, cbi) from LDS: half*32768 + tj*8192 + cbi*1024 + lane*16 B
    const unsigned char* bbase = bsh + half * 32768 + lane * 16;
#define BLOAD(tj, cbi) (*(const bf16x8*)(bbase + (tj) * 8192 + (cbi) * 1024))

    // Prefetch tile-0 iter-0 A frags (hi 4 + lo 4).
    bf16x8 xh0 = ALOAD(abase, 0, 0), xh1 = ALOAD(abase, 1, 0),
           xh2 = ALOAD(abase, 2, 0), xh3 = ALOAD(abase, 3, 0);
    bf16x8 xl0 = ALOAD(abase, 0, 2), xl1 = ALOAD(abase, 1, 2),
           xl2 = ALOAD(abase, 2, 2), xl3 = ALOAD(abase, 3, 2);
    bf16x8 yh0, yh1, yh2, yh3, yl0, yl1, yl2, yl3;

    // Stage this block's B tile (rsw + by*64KB, contiguous) into LDS, once.
    // 256 threads x 16B -> 16 passes.
    {
        const char* bsrc = (const char*)rsw + (size_t)by * 65536 + (size_t)t * 16;
        #pragma unroll
        for (int i = 0; i < 16; ++i)
            __builtin_amdgcn_global_load_lds(
                (const __attribute__((address_space(1))) unsigned int*)(bsrc + i * 4096),
                (__attribute__((address_space(3))) unsigned int*)(bsh + i * 4096 + t * 16),
                16, 0, 0);
    }
    __syncthreads();

#define MFMA __builtin_amdgcn_mfma_f32_16x16x32_bf16
#define BATCH(A0, A1, A2, A3, B0, B1, B2, B3)               \
    acc[0][0] = MFMA(A0, B0, acc[0][0], 0, 0, 0);           \
    acc[0][1] = MFMA(A0, B1, acc[0][1], 0, 0, 0);           \
    acc[0][2] = MFMA(A0, B2, acc[0][2], 0, 0, 0);           \
    acc[0][3] = MFMA(A0, B3, acc[0][3], 0, 0, 0);           \
    acc[1][0] = MFMA(A1, B0, acc[1][0], 0, 0, 0);           \
    acc[1][1] = MFMA(A1, B1, acc[1][1], 0, 0, 0);           \
    acc[1][2] = MFMA(A1, B2, acc[1][2], 0, 0, 0);           \
    acc[1][3] = MFMA(A1, B3, acc[1][3], 0, 0, 0);           \
    acc[2][0] = MFMA(A2, B0, acc[2][0], 0, 0, 0);           \
    acc[2][1] = MFMA(A2, B1, acc[2][1], 0, 0, 0);           \
    acc[2][2] = MFMA(A2, B2, acc[2][2], 0, 0, 0);           \
    acc[2][3] = MFMA(A2, B3, acc[2][3], 0, 0, 0);           \
    acc[3][0] = MFMA(A3, B0, acc[3][0], 0, 0, 0);           \
    acc[3][1] = MFMA(A3, B1, acc[3][1], 0, 0, 0);           \
    acc[3][2] = MFMA(A3, B2, acc[3][2], 0, 0, 0);           \
    acc[3][3] = MFMA(A3, B3, acc[3][3], 0, 0, 0);

// One (ks,kk) step: prefetch next A frag group (8 global loads), read B-hi
// (4 ds_read), hh + lh (32 MFMA), read B-lo, hl (16 MFMA).
#define ITER(CH, cH0, cH1, cH2, cH3, cL0, cL1, cL2, cL3,                 \
             PBASE, NH, nH0, nH1, nH2, nH3, nL0, nL1, nL2, nL3)          \
    {                                                                    \
        nH0 = ALOAD(PBASE, 0, NH);       nH1 = ALOAD(PBASE, 1, NH);      \
        nH2 = ALOAD(PBASE, 2, NH);       nH3 = ALOAD(PBASE, 3, NH);      \
        nL0 = ALOAD(PBASE, 0, (NH) + 2); nL1 = ALOAD(PBASE, 1, (NH) + 2);\
        nL2 = ALOAD(PBASE, 2, (NH) + 2); nL3 = ALOAD(PBASE, 3, (NH) + 2);\
        bf16x8 b0 = BLOAD(0, CH), b1 = BLOAD(1, CH),                     \
               b2 = BLOAD(2, CH), b3 = BLOAD(3, CH);                     \
        BATCH(cH0, cH1, cH2, cH3, b0, b1, b2, b3)      /* hi*hi */       \
        BATCH(cL0, cL1, cL2, cL3, b0, b1, b2, b3)      /* lo*hi */       \
        b0 = BLOAD(0, (CH) + 2); b1 = BLOAD(1, (CH) + 2);                \
        b2 = BLOAD(2, (CH) + 2); b3 = BLOAD(3, (CH) + 2);                \
        BATCH(cH0, cH1, cH2, cH3, b0, b1, b2, b3)      /* hi*lo */       \
    }

    #pragma unroll
    for (int i = 0; i < NTPB; ++i) {
        const __bf16* ab = abase + (size_t)i * TILE_STRIDE;
        const __bf16* an = (i + 1 < NTPB) ? (ab + TILE_STRIDE) : ab;

        f32x4 acc[4][4];
        #pragma unroll
        for (int ti = 0; ti < 4; ++ti)
            #pragma unroll
            for (int tj = 0; tj < 4; ++tj)
                acc[ti][tj] = (f32x4){0.f, 0.f, 0.f, 0.f};

        // cbi_h sequence over (ks,kk) = (0,0),(0,1),(1,0),(1,1): {0,1,4,5}
        ITER(0, xh0, xh1, xh2, xh3, xl0, xl1, xl2, xl3,
             ab, 1, yh0, yh1, yh2, yh3, yl0, yl1, yl2, yl3)
        ITER(1, yh0, yh1, yh2, yh3, yl0, yl1, yl2, yl3,
             ab, 4, xh0, xh1, xh2, xh3, xl0, xl1, xl2, xl3)
        ITER(4, xh0, xh1, xh2, xh3, xl0, xl1, xl2, xl3,
             ab, 5, yh0, yh1, yh2, yh3, yl0, yl1, yl2, yl3)
        ITER(5, yh0, yh1, yh2, yh3, yl0, yl1, yl2, yl3,
             an, 0, xh0, xh1, xh2, xh3, xl0, xl1, xl2, xl3)

        // Sign-pack via ballot; C/D layout (m89): col=lane&15, row=quad*4+reg.
        // TRANSPOSED store: codes_t[word][row].
        const int row0 = (bx0 + i) * TM;
        #pragma unroll
        for (int ti = 0; ti < 4; ++ti) {
            #pragma unroll
            for (int rg = 0; rg < 4; ++rg) {
                unsigned long long b[4];
                #pragma unroll
                for (int tj = 0; tj < 4; ++tj)
                    b[tj] = __ballot(acc[ti][tj][rg] > 0.f);
                if (col < 2) {
                    const int w = col;
                    unsigned int lo16 = (unsigned int)(b[2 * w]     >> (16 * quad)) & 0xFFFFu;
                    unsigned int hi16 = (unsigned int)(b[2 * w + 1] >> (16 * quad)) & 0xFFFFu;
                    const int row = row0 + wrow + ti * 16 + quad * 4 + rg;
                    const int wg  = by * 4 + half * 2 + w;
                    codes_t[(size_t)wg * NROWS + row] = lo16 | (hi16 << 16);
                }
            }
        }
    }

#undef ITER
#undef BATCH
#undef MFMA
#undef BLOAD
#undef ALOAD
}

// ---- Stage 2: Hamming -> cos (HW v_cos) -> mask -> out ---------------------
// Verified popc version (near its VALU floor ~5us). grid: 2048 blocks.
__global__ __launch_bounds__(256) void simmat_kernel(
    const unsigned int* __restrict__ codes_t,
    const int* __restrict__ qtok, const int* __restrict__ dtok,
    float* __restrict__ out)
{
    __shared__ unsigned int qc[8 * 36];

    const int blk  = blockIdx.x;
    const int ct   = blk & 3;
    const int asub = (blk >> 2) & 7;
    const int b    = (blk >> 5) & 31;
    const int l    = blk >> 10;
    const int t    = threadIdx.x;

    const int a0 = asub * 8;
    const int qrow0 = (l * BAT_ + b) * A_ + a0;
    if (t < 256) {
        int w = t >> 3, a = t & 7;
        qc[a * 36 + w] = codes_t[(size_t)w * NROWS + qrow0 + a];
    }
    __syncthreads();

    const int c = ct * 256 + t;
    const size_t drow = (size_t)NQROWS + (size_t)(l * BAT_ + b) * B_ + c;
    unsigned int dc[NW];
    #pragma unroll
    for (int w = 0; w < NW; ++w) dc[w] = codes_t[(size_t)w * NROWS + drow];
    const float dm = (dtok[b * B_ + c] != 0) ? 1.f : 0.f;

    float* obase = out + ((size_t)((b * L_ + l) * A_ + a0)) * B_ + c;
    #pragma unroll
    for (int ai = 0; ai < 8; ++ai) {
        int ham = 0;
        #pragma unroll
        for (int m = 0; m < 8; ++m) {
            uint4 qv = *(const uint4*)(&qc[ai * 36 + m * 4]);
            ham += __popc(qv.x ^ dc[4 * m])     + __popc(qv.y ^ dc[4 * m + 1])
                 + __popc(qv.z ^ dc[4 * m + 2]) + __popc(qv.w ^ dc[4 * m + 3]);
        }
        const float qmv = (qtok[b * A_ + a0 + ai] != 0) ? 1.f : 0.f;
        float sim = __cosf((float)M_PI / (float)NBITS_ * (float)ham);
        obase[(size_t)ai * B_] = sim * (qmv * dm);
    }
}

extern "C" void kernel_launch(void* const* d_in, const int* in_sizes, int n_in,
                              void* d_out, int out_size, void* d_ws, size_t ws_size,
                              hipStream_t stream) {
    const float* qe  = (const float*)d_in[0];  // [L,BAT,A,D]
    const float* de  = (const float*)d_in[1];  // [L,BAT,B,D]
    const int* qtok  = (const int*)d_in[2];    // [BAT,A]
    const int* dtok  = (const int*)d_in[3];    // [BAT,B]
    const float* r   = (const float*)d_in[4];  // [NBITS,D]
    float* out = (float*)d_out;                // [BAT,L,A,B] fp32

    // ws: [0, 8.5MB) codes_t | [8.5, 9.0MB) rsw | [9.0MB, +34MB) asw
    unsigned int* codes_t = (unsigned int*)d_ws;                    // 8912896 B
    __bf16* rsw = (__bf16*)((char*)d_ws + 8912896);                 // 524288 B
    __bf16* asw = (__bf16*)((char*)d_ws + 8912896 + 524288);        // 35651584 B

    preswz_kernel<<<NAGRP + NBGRP, 256, 0, stream>>>(qe, de, r, asw, rsw);
    hash_kernel<<<(NXB / NTPB) * NYB, 256, 0, stream>>>(asw, rsw, codes_t);
    simmat_kernel<<<L_ * BAT_ * 8 * 4, 256, 0, stream>>>(codes_t, qtok, dtok, out);
}

// Round 11
// 160.364 us; speedup vs baseline: 1.0274x; 1.0274x over previous
//
#include <hip/hip_runtime.h>
#include <math.h>

#define L_ 2
#define BAT_ 32
#define A_ 64
#define B_ 1024
#define D_ 128
#define NBITS_ 1024
#define NW 32                 // u32 words per code (1024 bits)
#define NQROWS (L_*BAT_*A_)   // 4096
#define NDROWS (L_*BAT_*B_)   // 65536
#define NROWS (NQROWS + NDROWS) // 69632
#define NAGRP (NROWS / 16)    // 4352 A-row groups of 16
#define NBGRP (NBITS_ / 16)   // 64 bit groups of 16

#define TM 128                // rows per tile
#define TN 128                // bits per tile
#define NXB (NROWS / TM)      // 544 x-tiles
#define NYB (NBITS_ / TN)     // 8 y-tiles
#define XPX (NXB / 8)         // 68 x-tiles per XCD
#define NTPB 4                // x-tiles per block (68 % 4 == 0)

typedef __bf16 bf16x8 __attribute__((ext_vector_type(8)));
typedef float  f32x4  __attribute__((ext_vector_type(4)));

// ---- Stage 0: split fp32 -> bf16 hi/lo AND swizzle into MFMA fragment order.
// Per 16-row group: layout [cbi:8][quad:4][col:16][8 bf16] = 4096 bf16 (8 KB).
// Verified (R0-R10, absmax 0.006149).
__global__ __launch_bounds__(256) void preswz_kernel(
    const float* __restrict__ qe, const float* __restrict__ de,
    const float* __restrict__ r, __bf16* __restrict__ asw,
    __bf16* __restrict__ rsw)
{
    const int g = blockIdx.x;       // 0..4415: A groups then r groups
    const int t = threadIdx.x;
    const int ks = t >> 7, kk = (t >> 6) & 1, quad = (t >> 4) & 3, col = t & 15;

    const float* src;
    __bf16* dst;
    if (g < NAGRP) {
        int row = g * 16 + col;
        src = (row < NQROWS) ? (qe + (size_t)row * D_)
                             : (de + (size_t)(row - NQROWS) * D_);
        dst = asw + (size_t)g * 4096;
    } else {
        int bit = (g - NAGRP) * 16 + col;
        src = r + (size_t)bit * D_;
        dst = rsw + (size_t)(g - NAGRP) * 4096;
    }

    const int ko = ks * 64 + kk * 32 + quad * 8;
    float4 v0 = *(const float4*)(src + ko);
    float4 v1 = *(const float4*)(src + ko + 4);
    bf16x8 hi, lo;
    hi[0] = (__bf16)v0.x; hi[1] = (__bf16)v0.y;
    hi[2] = (__bf16)v0.z; hi[3] = (__bf16)v0.w;
    hi[4] = (__bf16)v1.x; hi[5] = (__bf16)v1.y;
    hi[6] = (__bf16)v1.z; hi[7] = (__bf16)v1.w;
    lo[0] = (__bf16)(v0.x - (float)hi[0]);
    lo[1] = (__bf16)(v0.y - (float)hi[1]);
    lo[2] = (__bf16)(v0.z - (float)hi[2]);
    lo[3] = (__bf16)(v0.w - (float)hi[3]);
    lo[4] = (__bf16)(v1.x - (float)hi[4]);
    lo[5] = (__bf16)(v1.y - (float)hi[5]);
    lo[6] = (__bf16)(v1.z - (float)hi[6]);
    lo[7] = (__bf16)(v1.w - (float)hi[7]);

    const int c_hi = ks * 16 + kk * 4 + quad;   // hl=0
    const int c_lo = c_hi + 8;                  // hl=1
    *(bf16x8*)(dst + (size_t)(c_hi * 16 + col) * 8) = hi;
    *(bf16x8*)(dst + (size_t)(c_lo * 16 + col) * 8) = lo;
}

// ---- Stage 1: LSH sign-hash — FINAL: R5 structure (verified 57.0us) --------
// 8 waves x (32x64) per 128x128 tile; B tile staged once to LDS, 4 x-tiles
// amortized per block; depth-1 A prefetch; XCD-aware mapping (FETCH
// 102->19.5MB); no barriers in the tile loop. Measured plateau: MfmaUtil
// 32-40% across 10 structural probes — serial resource sum (MFMA 1862 +
// LDS 1024 + L2-A 1170 cyc/round) bounds this structure at ~46%; escape
// attempts in both directions (fewer/fatter waves R10, more regs R6,
// persistence R4, B-prefetch R9) all confirmed the model's falsifiers.
__global__ __launch_bounds__(512, 4) void hash_kernel(
    const __bf16* __restrict__ asw, const __bf16* __restrict__ rsw,
    unsigned int* __restrict__ codes_t)
{
    __shared__ __align__(16) unsigned char bsh[65536];

    const int t = threadIdx.x;
    const int lane = t & 63;
    const int quad = lane >> 4;       // 0..3
    const int col  = lane & 15;       // 0..15
    const int wv   = __builtin_amdgcn_readfirstlane(t >> 6);  // wave 0..7

    const int bid = blockIdx.x;       // 0..1087
    const int xcd = bid & 7;
    const int s   = bid >> 3;         // 0..135
    const int by  = s & 7;
    const int xq  = s >> 3;           // 0..16
    const int bx0 = xcd * XPX + xq * NTPB;

    const int wrow = (wv >> 1) * 32;  // 4 wave-rows of 32
    const int half = wv & 1;          // 2 wave-cols of 64 bits

    // A frag (ti, cbi) at pointer P: P + (ti*8 + cbi)*512 elems
    const __bf16* abase = asw + ((size_t)((bx0 * TM + wrow) >> 4)) * 4096
                              + (size_t)lane * 8;
#define ALOAD(P, ti, cbi) (*(const bf16x8*)((P) + ((ti) * 8 + (cbi)) * 512))
#define TILE_STRIDE 32768   /* 8 groups * 4096 elems */

    // B frag (tj, cbi) from LDS: half*32768 + tj*8192 + cbi*1024 + lane*16 B
    const unsigned char* bbase = bsh + half * 32768 + lane * 16;
#define BLOAD(tj, cbi) (*(const bf16x8*)(bbase + (tj) * 8192 + (cbi) * 1024))

    // Prefetch tile-0 iter-0 A frags; they complete by the staging barrier.
    bf16x8 xh0 = ALOAD(abase, 0, 0), xh1 = ALOAD(abase, 1, 0);
    bf16x8 xl0 = ALOAD(abase, 0, 2), xl1 = ALOAD(abase, 1, 2);
    bf16x8 yh0, yh1, yl0, yl1;

    // Stage this block's B tile (rsw + by*64KB, contiguous) into LDS, once.
    {
        const char* bsrc = (const char*)rsw + (size_t)by * 65536 + (size_t)t * 16;
        #pragma unroll
        for (int i = 0; i < 8; ++i)
            __builtin_amdgcn_global_load_lds(
                (const __attribute__((address_space(1))) unsigned int*)(bsrc + i * 8192),
                (__attribute__((address_space(3))) unsigned int*)(bsh + i * 8192 + t * 16),
                16, 0, 0);
    }
    __syncthreads();

#define MFMA __builtin_amdgcn_mfma_f32_16x16x32_bf16
#define BATCH(A0, A1, B0, B1, B2, B3)                       \
    acc[0][0] = MFMA(A0, B0, acc[0][0], 0, 0, 0);           \
    acc[0][1] = MFMA(A0, B1, acc[0][1], 0, 0, 0);           \
    acc[0][2] = MFMA(A0, B2, acc[0][2], 0, 0, 0);           \
    acc[0][3] = MFMA(A0, B3, acc[0][3], 0, 0, 0);           \
    acc[1][0] = MFMA(A1, B0, acc[1][0], 0, 0, 0);           \
    acc[1][1] = MFMA(A1, B1, acc[1][1], 0, 0, 0);           \
    acc[1][2] = MFMA(A1, B2, acc[1][2], 0, 0, 0);           \
    acc[1][3] = MFMA(A1, B3, acc[1][3], 0, 0, 0);

#define ITER(CH, cH0, cH1, cL0, cL1, PBASE, NH, nH0, nH1, nL0, nL1)     \
    {                                                                    \
        nH0 = ALOAD(PBASE, 0, NH);       nH1 = ALOAD(PBASE, 1, NH);      \
        nL0 = ALOAD(PBASE, 0, (NH) + 2); nL1 = ALOAD(PBASE, 1, (NH) + 2);\
        bf16x8 b0 = BLOAD(0, CH), b1 = BLOAD(1, CH),                     \
               b2 = BLOAD(2, CH), b3 = BLOAD(3, CH);                     \
        BATCH(cH0, cH1, b0, b1, b2, b3)      /* hi*hi */                 \
        BATCH(cL0, cL1, b0, b1, b2, b3)      /* lo*hi */                 \
        b0 = BLOAD(0, (CH) + 2); b1 = BLOAD(1, (CH) + 2);                \
        b2 = BLOAD(2, (CH) + 2); b3 = BLOAD(3, (CH) + 2);                \
        BATCH(cH0, cH1, b0, b1, b2, b3)      /* hi*lo */                 \
    }

    #pragma unroll
    for (int i = 0; i < NTPB; ++i) {
        const __bf16* ab = abase + (size_t)i * TILE_STRIDE;
        const __bf16* an = (i + 1 < NTPB) ? (ab + TILE_STRIDE) : ab;

        f32x4 acc[2][4];
        #pragma unroll
        for (int ti = 0; ti < 2; ++ti)
            #pragma unroll
            for (int tj = 0; tj < 4; ++tj)
                acc[ti][tj] = (f32x4){0.f, 0.f, 0.f, 0.f};

        // cbi_h sequence over (ks,kk) = (0,0),(0,1),(1,0),(1,1): {0,1,4,5}
        ITER(0, xh0, xh1, xl0, xl1, ab, 1, yh0, yh1, yl0, yl1)
        ITER(1, yh0, yh1, yl0, yl1, ab, 4, xh0, xh1, xl0, xl1)
        ITER(4, xh0, xh1, xl0, xl1, ab, 5, yh0, yh1, yl0, yl1)
        ITER(5, yh0, yh1, yl0, yl1, an, 0, xh0, xh1, xl0, xl1)

        // Sign-pack via ballot; C/D layout (m89): col=lane&15, row=quad*4+reg.
        // TRANSPOSED store: codes_t[word][row]. No barrier after -> epilogue
        // overlaps the next tile's prefetched A loads.
        const int row0 = (bx0 + i) * TM;
        #pragma unroll
        for (int ti = 0; ti < 2; ++ti) {
            #pragma unroll
            for (int rg = 0; rg < 4; ++rg) {
                unsigned long long b[4];
                #pragma unroll
                for (int tj = 0; tj < 4; ++tj)
                    b[tj] = __ballot(acc[ti][tj][rg] > 0.f);
                if (col < 2) {
                    const int w = col;
                    unsigned int lo16 = (unsigned int)(b[2 * w]     >> (16 * quad)) & 0xFFFFu;
                    unsigned int hi16 = (unsigned int)(b[2 * w + 1] >> (16 * quad)) & 0xFFFFu;
                    const int row = row0 + wrow + ti * 16 + quad * 4 + rg;
                    const int wg  = by * 4 + half * 2 + w;
                    codes_t[(size_t)wg * NROWS + row] = lo16 | (hi16 << 16);
                }
            }
        }
    }

#undef ITER
#undef BATCH
#undef MFMA
#undef BLOAD
#undef ALOAD
}

// ---- Stage 2: Hamming -> cos (HW v_cos) -> mask -> out ---------------------
// FINAL: verified popc version, near its VALU floor (~5us: 6.3M wave-ops x
// 2cyc / 1024 SIMDs). R8 proved the i8-MFMA alternative is slower (+6us:
// 1 wave/SIMD, long dependent unpack chain). grid: 2048 blocks, 8/CU.
__global__ __launch_bounds__(256) void simmat_kernel(
    const unsigned int* __restrict__ codes_t,
    const int* __restrict__ qtok, const int* __restrict__ dtok,
    float* __restrict__ out)
{
    __shared__ unsigned int qc[8 * 36];

    const int blk  = blockIdx.x;
    const int ct   = blk & 3;
    const int asub = (blk >> 2) & 7;
    const int b    = (blk >> 5) & 31;
    const int l    = blk >> 10;
    const int t    = threadIdx.x;

    const int a0 = asub * 8;
    const int qrow0 = (l * BAT_ + b) * A_ + a0;
    if (t < 256) {
        int w = t >> 3, a = t & 7;
        qc[a * 36 + w] = codes_t[(size_t)w * NROWS + qrow0 + a];
    }
    __syncthreads();

    const int c = ct * 256 + t;
    const size_t drow = (size_t)NQROWS + (size_t)(l * BAT_ + b) * B_ + c;
    unsigned int dc[NW];
    #pragma unroll
    for (int w = 0; w < NW; ++w) dc[w] = codes_t[(size_t)w * NROWS + drow];
    const float dm = (dtok[b * B_ + c] != 0) ? 1.f : 0.f;

    float* obase = out + ((size_t)((b * L_ + l) * A_ + a0)) * B_ + c;
    #pragma unroll
    for (int ai = 0; ai < 8; ++ai) {
        int ham = 0;
        #pragma unroll
        for (int m = 0; m < 8; ++m) {
            uint4 qv = *(const uint4*)(&qc[ai * 36 + m * 4]);
            ham += __popc(qv.x ^ dc[4 * m])     + __popc(qv.y ^ dc[4 * m + 1])
                 + __popc(qv.z ^ dc[4 * m + 2]) + __popc(qv.w ^ dc[4 * m + 3]);
        }
        const float qmv = (qtok[b * A_ + a0 + ai] != 0) ? 1.f : 0.f;
        float sim = __cosf((float)M_PI / (float)NBITS_ * (float)ham);
        obase[(size_t)ai * B_] = sim * (qmv * dm);
    }
}

extern "C" void kernel_launch(void* const* d_in, const int* in_sizes, int n_in,
                              void* d_out, int out_size, void* d_ws, size_t ws_size,
                              hipStream_t stream) {
    const float* qe  = (const float*)d_in[0];  // [L,BAT,A,D]
    const float* de  = (const float*)d_in[1];  // [L,BAT,B,D]
    const int* qtok  = (const int*)d_in[2];    // [BAT,A]
    const int* dtok  = (const int*)d_in[3];    // [BAT,B]
    const float* r   = (const float*)d_in[4];  // [NBITS,D]
    float* out = (float*)d_out;                // [BAT,L,A,B] fp32

    // ws: [0, 8.5MB) codes_t | [8.5, 9.0MB) rsw | [9.0MB, +34MB) asw
    unsigned int* codes_t = (unsigned int*)d_ws;                    // 8912896 B
    __bf16* rsw = (__bf16*)((char*)d_ws + 8912896);                 // 524288 B
    __bf16* asw = (__bf16*)((char*)d_ws + 8912896 + 524288);        // 35651584 B

    preswz_kernel<<<NAGRP + NBGRP, 256, 0, stream>>>(qe, de, r, asw, rsw);
    hash_kernel<<<(NXB / NTPB) * NYB, 512, 0, stream>>>(asw, rsw, codes_t);
    simmat_kernel<<<L_ * BAT_ * 8 * 4, 256, 0, stream>>>(codes_t, qtok, dtok, out);
}